// Round 6
// baseline (193.140 us; speedup 1.0000x reference)
//
#include <hip/hip_runtime.h>
#include <math.h>

#define H 768
#define S 256
#define NB 4      // batch
#define TOPK 4
#define L 4
#define NH 8      // biaffine h-split chunks (96 h each)

// 2/ln2: tanh(x) = 1 - 2/(2^(C*x)+1)
#define CSCALE 2.8853900817779268f

typedef __bf16 bf16x8 __attribute__((ext_vector_type(8)));
typedef float floatx4 __attribute__((ext_vector_type(4)));

// Native-rate transcendentals (v_exp_f32 / v_rcp_f32). exp2f()/expf() without
// -ffast-math are OCML precise libcalls (~20 VALU ops) -- round 3's lesson.
__device__ __forceinline__ float exp2_native(float x) {
#if __has_builtin(__builtin_amdgcn_exp2f)
  return __builtin_amdgcn_exp2f(x);
#else
  float r; asm("v_exp_f32 %0, %1" : "=v"(r) : "v"(x)); return r;
#endif
}
__device__ __forceinline__ float rcp_native(float x) {
#if __has_builtin(__builtin_amdgcn_rcpf)
  return __builtin_amdgcn_rcpf(x);
#else
  float r; asm("v_rcp_f32 %0, %1" : "=v"(r) : "v"(x)); return r;
#endif
}

// tanh for the dense epilogue (passing since round 2; __expf is native-rate)
__device__ __forceinline__ float fast_tanh(float x) {
  float cx = fminf(15.f, fmaxf(-15.f, x));
  float e = __expf(cx + cx);
  return __fdividef(e - 1.f, e + 1.f);
}

// ---------------------------------------------------------------------------
// Stage 0: pooled -> (Ah,Al) hi/lo bf16; concat(Wa,Ua) -> (Wh,Wl); dense_w -> Dh.
__global__ __launch_bounds__(256) void cvt_kernel(
    const float* __restrict__ pooled, const float* __restrict__ Wa_w,
    const float* __restrict__ Ua_w, const float* __restrict__ dense_w,
    __bf16* __restrict__ Ah, __bf16* __restrict__ Al,
    __bf16* __restrict__ Wh, __bf16* __restrict__ Wl,
    __bf16* __restrict__ Dh) {
  const int NA4 = (NB * S * H) / 4;       // 196608
  const int NW4 = (2 * H * H) / 4;        // 294912 (Wa then Ua)
  const int NWa4 = (H * H) / 4;           // 147456
  const int ND4 = (H * 2 * H) / 4;        // 294912
  int i = blockIdx.x * 256 + threadIdx.x;
  if (i >= NA4 + NW4 + ND4) return;
  if (i >= NA4 + NW4) {  // dense_w: hi only
    int w = i - NA4 - NW4;
    float4 v = ((const float4*)dense_w)[w];
    union { __bf16 h[4]; ushort4 u; } tmp;
    tmp.h[0] = (__bf16)v.x; tmp.h[1] = (__bf16)v.y;
    tmp.h[2] = (__bf16)v.z; tmp.h[3] = (__bf16)v.w;
    *(ushort4*)(Dh + (size_t)w * 4) = tmp.u;
    return;
  }
  float4 v;
  __bf16 *hi, *lo;
  if (i < NA4) {
    v = ((const float4*)pooled)[i];
    hi = Ah + i * 4; lo = Al + i * 4;
  } else {
    int w = i - NA4;
    v = (w < NWa4) ? ((const float4*)Wa_w)[w] : ((const float4*)Ua_w)[w - NWa4];
    hi = Wh + (size_t)w * 4; lo = Wl + (size_t)w * 4;
  }
  union { __bf16 h[4]; ushort4 u; } a, b;
  float f[4] = {v.x, v.y, v.z, v.w};
#pragma unroll
  for (int k = 0; k < 4; ++k) {
    __bf16 h = (__bf16)f[k];
    a.h[k] = h;
    b.h[k] = (__bf16)(f[k] - (float)h);
  }
  *(ushort4*)hi = a.u;
  *(ushort4*)lo = b.u;
}

// ---------------------------------------------------------------------------
// Stage 1 (split-bf16 MFMA): hij[m][n] = CSCALE*(pooled[m,:].W[n,:] + bias[n]).
// 32x64 tile -> grid 32x24 = 768 blocks = 3 blocks/CU. 3 MFMA terms (hh+hl+lh).
__global__ __launch_bounds__(256) void proj_mfma(
    const __bf16* __restrict__ Ah, const __bf16* __restrict__ Al,
    const __bf16* __restrict__ Wh, const __bf16* __restrict__ Wl,
    const float* __restrict__ Wa_b, const float* __restrict__ Ua_b,
    float* __restrict__ hij) {
  __shared__ __align__(16) __bf16 Ahs[32][40];
  __shared__ __align__(16) __bf16 Als[32][40];
  __shared__ __align__(16) __bf16 Bhs[64][40];
  __shared__ __align__(16) __bf16 Bls[64][40];
  const int m0 = blockIdx.x * 32;
  const int n0 = blockIdx.y * 64;
  const int t = threadIdx.x;
  const int arow = t >> 3;            // 0..31
  const int kq4 = (t & 7) * 4;        // 8B chunks
  const __bf16* Arh = Ah + (size_t)(m0 + arow) * H;
  const __bf16* Arl = Al + (size_t)(m0 + arow) * H;
  const int brow = t >> 2;            // 0..63
  const int kq8 = (t & 3) * 8;        // 16B chunks
  const __bf16* Brh = Wh + (size_t)(n0 + brow) * H;
  const __bf16* Brl = Wl + (size_t)(n0 + brow) * H;
  const int lane = t & 63;
  const int wave = t >> 6;
  const int wn = wave * 16;
  const int fm = lane & 15;
  const int quad = lane >> 4;
  floatx4 acc[2] = {};

  for (int kc = 0; kc < H; kc += 32) {
    *(ushort4*)&Ahs[arow][kq4] = *(const ushort4*)&Arh[kc + kq4];
    *(ushort4*)&Als[arow][kq4] = *(const ushort4*)&Arl[kc + kq4];
    *(bf16x8*)&Bhs[brow][kq8] = *(const bf16x8*)&Brh[kc + kq8];
    *(bf16x8*)&Bls[brow][kq8] = *(const bf16x8*)&Brl[kc + kq8];
    __syncthreads();
    bf16x8 afh[2], afl[2], bfh, bfl;
#pragma unroll
    for (int i = 0; i < 2; ++i) {
      afh[i] = *(const bf16x8*)&Ahs[i * 16 + fm][quad * 8];
      afl[i] = *(const bf16x8*)&Als[i * 16 + fm][quad * 8];
    }
    bfh = *(const bf16x8*)&Bhs[wn + fm][quad * 8];
    bfl = *(const bf16x8*)&Bls[wn + fm][quad * 8];
#pragma unroll
    for (int i = 0; i < 2; ++i) {
      acc[i] = __builtin_amdgcn_mfma_f32_16x16x32_bf16(afh[i], bfh, acc[i], 0, 0, 0);
      acc[i] = __builtin_amdgcn_mfma_f32_16x16x32_bf16(afh[i], bfl, acc[i], 0, 0, 0);
      acc[i] = __builtin_amdgcn_mfma_f32_16x16x32_bf16(afl[i], bfh, acc[i], 0, 0, 0);
    }
    __syncthreads();
  }
  const int col = n0 + wn + fm;
  const float bias = (col < H) ? Wa_b[col] : Ua_b[col - H];
#pragma unroll
  for (int i = 0; i < 2; ++i)
#pragma unroll
    for (int rg = 0; rg < 4; ++rg) {
      const int row = m0 + i * 16 + quad * 4 + rg;
      hij[(size_t)row * 1536 + col] = CSCALE * (acc[i][rg] + bias);
    }
}

// ---------------------------------------------------------------------------
// Stage 2: partial[ch][b,a,c] = Sva_ch + sum_{h in ch} (-2 va[h]) * rcp(2^(xi+xj)+1)
// 32x32 (a,c) tile, 2x2/thread, NH=8 chunks of 96 h -> 2048 blocks = 8/CU.
// Single-barrier double-buffered pipeline (validated round 5).
__global__ __launch_bounds__(256) void biaffine4(
    const float* __restrict__ hij, const float* __restrict__ va,
    float* __restrict__ partials) {
  __shared__ __align__(16) float his[2][16][34];  // [buf][h][c]
  __shared__ __align__(16) float hjs[2][16][34];  // [buf][h][a]
  __shared__ __align__(16) float vas2[96];
  __shared__ float svas;
  const int z = blockIdx.z;
  const int b = z >> 3;
  const int ch = z & 7;
  const int hc0 = ch * 96;
  const int a0 = blockIdx.y * 32;
  const int c0 = blockIdx.x * 32;
  const int t = threadIdx.x;
  if (t < 96) vas2[t] = -2.f * va[hc0 + t];
  __syncthreads();
  if (t < 64) {
    float s = vas2[t] + ((t < 32) ? vas2[t + 64] : 0.f);
#pragma unroll
    for (int off = 32; off > 0; off >>= 1) s += __shfl_xor(s, off);
    if (t == 0) svas = -0.5f * s;
  }
  const int lh = t & 15;
  const int lr = t >> 4;
  const int ca = (t & 15) * 2;
  const int aa = (t >> 4) * 2;
  const float* pi0b = hij + (size_t)(b * S + c0 + lr) * 1536 + hc0 + lh;
  const float* pi1b = hij + (size_t)(b * S + c0 + lr + 16) * 1536 + hc0 + lh;
  const float* pj0b = hij + (size_t)(b * S + a0 + lr) * 1536 + 768 + hc0 + lh;
  const float* pj1b = hij + (size_t)(b * S + a0 + lr + 16) * 1536 + 768 + hc0 + lh;
  float acc00 = 0.f, acc01 = 0.f, acc10 = 0.f, acc11 = 0.f;

  float pi0 = pi0b[0], pi1 = pi1b[0], pj0 = pj0b[0], pj1 = pj1b[0];
  for (int hr = 0; hr < 96; hr += 16) {
    const int bf = (hr >> 4) & 1;
    his[bf][lh][lr]      = pi0;
    his[bf][lh][lr + 16] = pi1;
    hjs[bf][lh][lr]      = pj0;
    hjs[bf][lh][lr + 16] = pj1;
    __syncthreads();  // single barrier per iter; buf^1 write is ordered after it
    if (hr + 16 < 96) {
      pi0 = pi0b[hr + 16]; pi1 = pi1b[hr + 16];
      pj0 = pj0b[hr + 16]; pj1 = pj1b[hr + 16];
    }
    float vreg[16];
    *(float4*)&vreg[0]  = *(const float4*)&vas2[hr + 0];
    *(float4*)&vreg[4]  = *(const float4*)&vas2[hr + 4];
    *(float4*)&vreg[8]  = *(const float4*)&vas2[hr + 8];
    *(float4*)&vreg[12] = *(const float4*)&vas2[hr + 12];
#pragma unroll
    for (int h = 0; h < 16; ++h) {
      float v = vreg[h];
      float2 xi = *(const float2*)&his[bf][h][ca];
      float2 xj = *(const float2*)&hjs[bf][h][aa];
      acc00 = fmaf(v, rcp_native(exp2_native(xi.x + xj.x) + 1.f), acc00);
      acc01 = fmaf(v, rcp_native(exp2_native(xi.y + xj.x) + 1.f), acc01);
      acc10 = fmaf(v, rcp_native(exp2_native(xi.x + xj.y) + 1.f), acc10);
      acc11 = fmaf(v, rcp_native(exp2_native(xi.y + xj.y) + 1.f), acc11);
    }
  }
  const float sv = svas;
  float* pout = partials + (size_t)ch * (NB * S * S);
  float2 r0 = {acc00 + sv, acc01 + sv};
  float2 r1 = {acc10 + sv, acc11 + sv};
  *(float2*)&pout[(b * S + a0 + aa) * S + c0 + ca]     = r0;
  *(float2*)&pout[(b * S + a0 + aa + 1) * S + c0 + ca] = r1;
}

// ---------------------------------------------------------------------------
// Stage 3: combine 8 partials -> logits (d_out) + top-4 per row; also zero
// out_type (this block's 16 floats) ahead of dense_mfma_fc's atomics.
__global__ __launch_bounds__(64) void topk_kernel(
    const float* __restrict__ partials, float* __restrict__ logits,
    int* __restrict__ idx, float* __restrict__ out_type) {
  const int row = blockIdx.x;  // b*S + a
  const int lane = threadIdx.x;
  if (lane < 4) {
    float4 z = {0.f, 0.f, 0.f, 0.f};
    *(float4*)&out_type[(size_t)row * 16 + lane * 4] = z;
  }
  const int P = NB * S * S;
  float v[4];
#pragma unroll
  for (int j = 0; j < 4; ++j) {
    int c = row * S + j * 64 + lane;
    float s0 = partials[c]         + partials[c + P];
    float s1 = partials[c + 2 * P] + partials[c + 3 * P];
    float s2 = partials[c + 4 * P] + partials[c + 5 * P];
    float s3 = partials[c + 6 * P] + partials[c + 7 * P];
    v[j] = (s0 + s1) + (s2 + s3);
    logits[c] = v[j];
  }
#pragma unroll
  for (int k = 0; k < TOPK; ++k) {
    float bestv = v[0];
    int besti = lane;
#pragma unroll
    for (int j = 1; j < 4; ++j) {
      int c = j * 64 + lane;
      if (v[j] > bestv) { bestv = v[j]; besti = c; }
    }
#pragma unroll
    for (int off = 32; off > 0; off >>= 1) {
      float ov = __shfl_xor(bestv, off);
      int oi = __shfl_xor(besti, off);
      if (ov > bestv || (ov == bestv && oi < besti)) { bestv = ov; besti = oi; }
    }
    int mj = besti >> 6, ml = besti & 63;
#pragma unroll
    for (int j = 0; j < 4; ++j)
      if (lane == ml && j == mj) v[j] = -3.402823466e38f;
    if (lane == 0) idx[row * TOPK + k] = besti;
  }
}

// ---------------------------------------------------------------------------
// Stage 4+5 fused: 64x64 bf16-MFMA tile of hidden = tanh(cat.dense_w^T + b);
// fc reduction done in REGISTERS (shfl over the 16 fm-lanes) -> atomicAdd.
// No hs LDS tile -> no bank conflicts (round 5's 4.7e6-cycle lesson).
__global__ __launch_bounds__(256) void dense_mfma_fc(
    const __bf16* __restrict__ Ah, const int* __restrict__ idx,
    const __bf16* __restrict__ Dh, const float* __restrict__ dense_b,
    const float* __restrict__ fc_w, const float* __restrict__ fc_b,
    float* __restrict__ out_type) {
  __shared__ __align__(16) __bf16 As[64][40];
  __shared__ __align__(16) __bf16 Bs[64][40];
  const int m0 = blockIdx.x * 64;
  const int n0 = blockIdx.y * 64;
  const int t = threadIdx.x;
  const int srow = t >> 2;
  const int kq8 = (t & 3) * 8;
  const int r = m0 + srow;
  const int kk = r & 3, s = (r >> 2) & 255, b = r >> 10;
  const __bf16* dep  = Ah + (size_t)(b * S + s) * H;
  const __bf16* head = Ah + (size_t)(b * S + idx[(b * S + s) * TOPK + kk]) * H;
  const __bf16* brow = Dh + (size_t)(n0 + srow) * (2 * H);
  const int lane = t & 63;
  const int wave = t >> 6;
  const int wm = (wave & 1) * 32;
  const int wn = (wave >> 1) * 32;
  const int fm = lane & 15;
  const int quad = lane >> 4;
  floatx4 acc[2][2] = {};

  for (int kc = 0; kc < 2 * H; kc += 32) {
    const __bf16* ap = (kc < H) ? (dep + kc) : (head + (kc - H));
    *(bf16x8*)&As[srow][kq8] = *(const bf16x8*)&ap[kq8];
    *(bf16x8*)&Bs[srow][kq8] = *(const bf16x8*)&brow[kc + kq8];
    __syncthreads();
    bf16x8 af[2], bfr[2];
#pragma unroll
    for (int i = 0; i < 2; ++i) {
      af[i]  = *(const bf16x8*)&As[wm + i * 16 + fm][quad * 8];
      bfr[i] = *(const bf16x8*)&Bs[wn + i * 16 + fm][quad * 8];
    }
#pragma unroll
    for (int i = 0; i < 2; ++i)
#pragma unroll
      for (int j = 0; j < 2; ++j)
        acc[i][j] = __builtin_amdgcn_mfma_f32_16x16x32_bf16(af[i], bfr[j], acc[i][j], 0, 0, 0);
    __syncthreads();
  }
  // tanh epilogue in registers
  float hval[2][2][4];
#pragma unroll
  for (int j = 0; j < 2; ++j) {
    const float bias = dense_b[n0 + wn + j * 16 + fm];
#pragma unroll
    for (int i = 0; i < 2; ++i)
#pragma unroll
      for (int rg = 0; rg < 4; ++rg)
        hval[i][j][rg] = fast_tanh(acc[i][j][rg] + bias);
  }
  // fc partials: p[i][rg][l] = h(i,0,rg)*w(l,col0) + h(i,1,rg)*w(l,col1)
  float p[2][4][4];
#pragma unroll
  for (int l = 0; l < L; ++l) {
    const float w0 = fc_w[l * H + n0 + wn + fm];
    const float w1 = fc_w[l * H + n0 + wn + 16 + fm];
#pragma unroll
    for (int i = 0; i < 2; ++i)
#pragma unroll
      for (int rg = 0; rg < 4; ++rg)
        p[i][rg][l] = fmaf(hval[i][0][rg], w0, hval[i][1][rg] * w1);
  }
  // butterfly over the 16 fm-lanes (quad bits untouched by xor 1,2,4,8)
#pragma unroll
  for (int step = 1; step < 16; step <<= 1)
#pragma unroll
    for (int i = 0; i < 2; ++i)
#pragma unroll
      for (int rg = 0; rg < 4; ++rg)
#pragma unroll
        for (int l = 0; l < L; ++l)
          p[i][rg][l] += __shfl_xor(p[i][rg][l], step);
  if (fm == 0) {
    const bool addb = (blockIdx.y == 0) && (wn == 0);
#pragma unroll
    for (int i = 0; i < 2; ++i)
#pragma unroll
      for (int rg = 0; rg < 4; ++rg) {
        const int row = m0 + wm + i * 16 + quad * 4 + rg;
#pragma unroll
        for (int l = 0; l < L; ++l)
          atomicAdd(&out_type[(size_t)row * L + l],
                    p[i][rg][l] + (addb ? fc_b[l] : 0.f));
      }
  }
}

// ---------------------------------------------------------------------------
extern "C" void kernel_launch(void* const* d_in, const int* in_sizes, int n_in,
                              void* d_out, int out_size, void* d_ws, size_t ws_size,
                              hipStream_t stream) {
  const float* pooled  = (const float*)d_in[0];
  const float* Wa_w    = (const float*)d_in[1];
  const float* Wa_b    = (const float*)d_in[2];
  const float* Ua_w    = (const float*)d_in[3];
  const float* Ua_b    = (const float*)d_in[4];
  const float* va_w    = (const float*)d_in[5];
  const float* dense_w = (const float*)d_in[6];
  const float* dense_b = (const float*)d_in[7];
  const float* fc_w    = (const float*)d_in[8];
  const float* fc_b    = (const float*)d_in[9];

  float* logits   = (float*)d_out;            // (4,256,256)
  float* out_type = logits + NB * S * S;      // (4,256,4,4) = 16384 floats

  // ws layout (~19.3 MB; aliasing: Wh/Wl live in the partials region and are
  // dead after proj, before biaffine writes partials):
  float*  hij      = (float*)d_ws;                     // 1,572,864 f (6 MB)
  float*  partials = hij + 1572864;                    // 2,097,152 f (8 MB)
  __bf16* Wh       = (__bf16*)partials;                //   1,179,648 bf16 (alias)
  __bf16* Wl       = Wh + 1179648;                     //   1,179,648 bf16 (alias)
  int*    idxbuf   = (int*)(partials + 2097152);       // 4096 ints
  __bf16* Ah       = (__bf16*)(idxbuf + NB * S * TOPK);// 786,432 bf16
  __bf16* Al       = Ah + 786432;                      // 786,432 bf16
  __bf16* Dh       = Al + 786432;                      // 1,179,648 bf16

  cvt_kernel<<<dim3(3072), 256, 0, stream>>>(pooled, Wa_w, Ua_w, dense_w,
                                             Ah, Al, Wh, Wl, Dh);
  proj_mfma<<<dim3(32, 24), 256, 0, stream>>>(Ah, Al, Wh, Wl, Wa_b, Ua_b, hij);
  biaffine4<<<dim3(8, 8, NB * NH), 256, 0, stream>>>(hij, va_w, partials);
  topk_kernel<<<dim3(1024), 64, 0, stream>>>(partials, logits, idxbuf, out_type);
  dense_mfma_fc<<<dim3(64, 12), 256, 0, stream>>>(Ah, idxbuf, Dh, dense_b,
                                                  fc_w, fc_b, out_type);
}

// Round 7
// 158.454 us; speedup vs baseline: 1.2189x; 1.2189x over previous
//
#include <hip/hip_runtime.h>
#include <math.h>

#define H 768
#define S 256
#define NB 4      // batch
#define TOPK 4
#define L 4
#define NH 8      // biaffine h-split chunks (96 h each)

// 2/ln2: tanh(x) = 1 - 2/(2^(C*x)+1)
#define CSCALE 2.8853900817779268f

typedef __bf16 bf16x8 __attribute__((ext_vector_type(8)));
typedef __bf16 bf16x4 __attribute__((ext_vector_type(4)));
typedef float floatx4 __attribute__((ext_vector_type(4)));

// Native-rate transcendentals. exp2f()/expf() without -ffast-math are OCML
// precise libcalls (~20 VALU ops) -- round 3's lesson.
__device__ __forceinline__ float exp2_native(float x) {
#if __has_builtin(__builtin_amdgcn_exp2f)
  return __builtin_amdgcn_exp2f(x);
#else
  float r; asm("v_exp_f32 %0, %1" : "=v"(r) : "v"(x)); return r;
#endif
}
__device__ __forceinline__ float rcp_native(float x) {
#if __has_builtin(__builtin_amdgcn_rcpf)
  return __builtin_amdgcn_rcpf(x);
#else
  float r; asm("v_rcp_f32 %0, %1" : "=v"(r) : "v"(x)); return r;
#endif
}

// tanh for the hidden epilogue (__expf is native-rate; passing since round 2)
__device__ __forceinline__ float fast_tanh(float x) {
  float cx = fminf(15.f, fmaxf(-15.f, x));
  float e = __expf(cx + cx);
  return __fdividef(e - 1.f, e + 1.f);
}

// ---------------------------------------------------------------------------
// Stage 0: pooled -> (Ah,Al) hi/lo bf16; concat(Wa,Ua) -> (Wh,Wl) hi/lo;
// dense_w -> Drow bf16, re-laid out as 1536 B-rows of length 768:
//   Drow[o]      = dense_w[o][0:768]     (dep half)
//   Drow[768+o]  = dense_w[o][768:1536]  (head half)
__global__ __launch_bounds__(256) void cvt_kernel(
    const float* __restrict__ pooled, const float* __restrict__ Wa_w,
    const float* __restrict__ Ua_w, const float* __restrict__ dense_w,
    __bf16* __restrict__ Ah, __bf16* __restrict__ Al,
    __bf16* __restrict__ Wh, __bf16* __restrict__ Wl,
    __bf16* __restrict__ Drow) {
  const int NA4 = (NB * S * H) / 4;       // 196608
  const int NW4 = (2 * H * H) / 4;        // 294912 (Wa then Ua)
  const int NWa4 = (H * H) / 4;           // 147456
  const int ND4 = (H * 2 * H) / 4;        // 294912
  int i = blockIdx.x * 256 + threadIdx.x;
  if (i >= NA4 + NW4 + ND4) return;
  if (i >= NA4 + NW4) {  // dense_w -> Drow (hi only)
    int w = i - NA4 - NW4;
    int o = w / 384;         // 1536/4 float4 per source row
    int k = (w - o * 384) * 4;
    float4 v = ((const float4*)dense_w)[w];
    union { __bf16 h[4]; ushort4 u; } tmp;
    tmp.h[0] = (__bf16)v.x; tmp.h[1] = (__bf16)v.y;
    tmp.h[2] = (__bf16)v.z; tmp.h[3] = (__bf16)v.w;
    int row = (k < H) ? o : (H + o);
    int col = (k < H) ? k : (k - H);
    *(ushort4*)(Drow + (size_t)row * H + col) = tmp.u;
    return;
  }
  float4 v;
  __bf16 *hi, *lo;
  if (i < NA4) {
    v = ((const float4*)pooled)[i];
    hi = Ah + i * 4; lo = Al + i * 4;
  } else {
    int w = i - NA4;
    v = (w < NWa4) ? ((const float4*)Wa_w)[w] : ((const float4*)Ua_w)[w - NWa4];
    hi = Wh + (size_t)w * 4; lo = Wl + (size_t)w * 4;
  }
  union { __bf16 h[4]; ushort4 u; } a, b;
  float f[4] = {v.x, v.y, v.z, v.w};
#pragma unroll
  for (int k = 0; k < 4; ++k) {
    __bf16 h = (__bf16)f[k];
    a.h[k] = h;
    b.h[k] = (__bf16)(f[k] - (float)h);
  }
  *(ushort4*)hi = a.u;
  *(ushort4*)lo = b.u;
}

// ---------------------------------------------------------------------------
// Stage 1 (one GEMM for everything): C = pooled(1024x768) @ B^T where B has
// 3072 rows: [0,1536) = concat(Wa,Ua) (hi/lo 3-term split for fp32-class
// accuracy -> hij, CSCALE-scaled, bit-identical to round 6); [1536,2304) =
// dense dep half (+dense_b -> dpb bf16); [2304,3072) = dense head half (-> hpb).
// 32x64 tile -> grid 32x48 = 1536 blocks = 6 blocks/CU (2x round 6's dense).
__global__ __launch_bounds__(256) void big_mfma(
    const __bf16* __restrict__ Ah, const __bf16* __restrict__ Al,
    const __bf16* __restrict__ Wh, const __bf16* __restrict__ Wl,
    const __bf16* __restrict__ Drow, const float* __restrict__ Wa_b,
    const float* __restrict__ Ua_b, const float* __restrict__ dense_b,
    float* __restrict__ hij, __bf16* __restrict__ dpb,
    __bf16* __restrict__ hpb) {
  __shared__ __align__(16) __bf16 Ahs[32][40];
  __shared__ __align__(16) __bf16 Als[32][40];
  __shared__ __align__(16) __bf16 Bhs[64][40];
  __shared__ __align__(16) __bf16 Bls[64][40];
  const int m0 = blockIdx.x * 32;
  const int n0 = blockIdx.y * 64;          // 0..3008
  const bool isproj = (n0 < 2 * H);
  const int t = threadIdx.x;
  const int arow = t >> 3;                 // 0..31
  const int kq4 = (t & 7) * 4;
  const __bf16* Arh = Ah + (size_t)(m0 + arow) * H;
  const __bf16* Arl = Al + (size_t)(m0 + arow) * H;
  const int brow = t >> 2;                 // 0..63
  const int kq8 = (t & 3) * 8;
  const __bf16* Brh = isproj ? (Wh + (size_t)(n0 + brow) * H)
                             : (Drow + (size_t)(n0 - 2 * H + brow) * H);
  const __bf16* Brl = Wl + (size_t)((isproj ? n0 : 0) + brow) * H;
  const int lane = t & 63;
  const int wave = t >> 6;
  const int wn = wave * 16;
  const int fm = lane & 15;
  const int quad = lane >> 4;
  floatx4 acc[2] = {};

  for (int kc = 0; kc < H; kc += 32) {
    *(ushort4*)&Ahs[arow][kq4] = *(const ushort4*)&Arh[kc + kq4];
    *(bf16x8*)&Bhs[brow][kq8] = *(const bf16x8*)&Brh[kc + kq8];
    if (isproj) {
      *(ushort4*)&Als[arow][kq4] = *(const ushort4*)&Arl[kc + kq4];
      *(bf16x8*)&Bls[brow][kq8] = *(const bf16x8*)&Brl[kc + kq8];
    }
    __syncthreads();
    bf16x8 afh[2], bfh;
#pragma unroll
    for (int i = 0; i < 2; ++i)
      afh[i] = *(const bf16x8*)&Ahs[i * 16 + fm][quad * 8];
    bfh = *(const bf16x8*)&Bhs[wn + fm][quad * 8];
    if (isproj) {
      bf16x8 afl[2], bfl;
#pragma unroll
      for (int i = 0; i < 2; ++i)
        afl[i] = *(const bf16x8*)&Als[i * 16 + fm][quad * 8];
      bfl = *(const bf16x8*)&Bls[wn + fm][quad * 8];
#pragma unroll
      for (int i = 0; i < 2; ++i) {  // hh, hl, lh: order identical to round 6
        acc[i] = __builtin_amdgcn_mfma_f32_16x16x32_bf16(afh[i], bfh, acc[i], 0, 0, 0);
        acc[i] = __builtin_amdgcn_mfma_f32_16x16x32_bf16(afh[i], bfl, acc[i], 0, 0, 0);
        acc[i] = __builtin_amdgcn_mfma_f32_16x16x32_bf16(afl[i], bfh, acc[i], 0, 0, 0);
      }
    } else {
#pragma unroll
      for (int i = 0; i < 2; ++i)
        acc[i] = __builtin_amdgcn_mfma_f32_16x16x32_bf16(afh[i], bfh, acc[i], 0, 0, 0);
    }
    __syncthreads();
  }
  const int col = n0 + wn + fm;
  if (col < 2 * H) {          // hij: CSCALE*(acc + proj bias)
    const float bias = (col < H) ? Wa_b[col] : Ua_b[col - H];
#pragma unroll
    for (int i = 0; i < 2; ++i)
#pragma unroll
      for (int rg = 0; rg < 4; ++rg) {
        const int row = m0 + i * 16 + quad * 4 + rg;
        hij[(size_t)row * 1536 + col] = CSCALE * (acc[i][rg] + bias);
      }
  } else if (col < 3 * H) {   // dp: + dense_b, bf16
    const int o = col - 2 * H;
    const float bias = dense_b[o];
#pragma unroll
    for (int i = 0; i < 2; ++i)
#pragma unroll
      for (int rg = 0; rg < 4; ++rg) {
        const int row = m0 + i * 16 + quad * 4 + rg;
        dpb[(size_t)row * H + o] = (__bf16)(acc[i][rg] + bias);
      }
  } else {                    // hp: raw, bf16
    const int o = col - 3 * H;
#pragma unroll
    for (int i = 0; i < 2; ++i)
#pragma unroll
      for (int rg = 0; rg < 4; ++rg) {
        const int row = m0 + i * 16 + quad * 4 + rg;
        hpb[(size_t)row * H + o] = (__bf16)acc[i][rg];
      }
  }
}

// ---------------------------------------------------------------------------
// Stage 2: partial[ch][b,a,c] = Sva_ch + sum_{h in ch} (-2 va[h]) * rcp(2^(xi+xj)+1)
// 32x32 (a,c) tile, 2x2/thread, NH=8 chunks of 96 h -> 2048 blocks.
// Single-barrier double-buffered pipeline (validated rounds 5-6).
__global__ __launch_bounds__(256) void biaffine4(
    const float* __restrict__ hij, const float* __restrict__ va,
    float* __restrict__ partials) {
  __shared__ __align__(16) float his[2][16][34];
  __shared__ __align__(16) float hjs[2][16][34];
  __shared__ __align__(16) float vas2[96];
  __shared__ float svas;
  const int z = blockIdx.z;
  const int b = z >> 3;
  const int ch = z & 7;
  const int hc0 = ch * 96;
  const int a0 = blockIdx.y * 32;
  const int c0 = blockIdx.x * 32;
  const int t = threadIdx.x;
  if (t < 96) vas2[t] = -2.f * va[hc0 + t];
  __syncthreads();
  if (t < 64) {
    float s = vas2[t] + ((t < 32) ? vas2[t + 64] : 0.f);
#pragma unroll
    for (int off = 32; off > 0; off >>= 1) s += __shfl_xor(s, off);
    if (t == 0) svas = -0.5f * s;
  }
  const int lh = t & 15;
  const int lr = t >> 4;
  const int ca = (t & 15) * 2;
  const int aa = (t >> 4) * 2;
  const float* pi0b = hij + (size_t)(b * S + c0 + lr) * 1536 + hc0 + lh;
  const float* pi1b = hij + (size_t)(b * S + c0 + lr + 16) * 1536 + hc0 + lh;
  const float* pj0b = hij + (size_t)(b * S + a0 + lr) * 1536 + 768 + hc0 + lh;
  const float* pj1b = hij + (size_t)(b * S + a0 + lr + 16) * 1536 + 768 + hc0 + lh;
  float acc00 = 0.f, acc01 = 0.f, acc10 = 0.f, acc11 = 0.f;

  float pi0 = pi0b[0], pi1 = pi1b[0], pj0 = pj0b[0], pj1 = pj1b[0];
  for (int hr = 0; hr < 96; hr += 16) {
    const int bf = (hr >> 4) & 1;
    his[bf][lh][lr]      = pi0;
    his[bf][lh][lr + 16] = pi1;
    hjs[bf][lh][lr]      = pj0;
    hjs[bf][lh][lr + 16] = pj1;
    __syncthreads();
    if (hr + 16 < 96) {
      pi0 = pi0b[hr + 16]; pi1 = pi1b[hr + 16];
      pj0 = pj0b[hr + 16]; pj1 = pj1b[hr + 16];
    }
    float vreg[16];
    *(float4*)&vreg[0]  = *(const float4*)&vas2[hr + 0];
    *(float4*)&vreg[4]  = *(const float4*)&vas2[hr + 4];
    *(float4*)&vreg[8]  = *(const float4*)&vas2[hr + 8];
    *(float4*)&vreg[12] = *(const float4*)&vas2[hr + 12];
#pragma unroll
    for (int h = 0; h < 16; ++h) {
      float v = vreg[h];
      float2 xi = *(const float2*)&his[bf][h][ca];
      float2 xj = *(const float2*)&hjs[bf][h][aa];
      acc00 = fmaf(v, rcp_native(exp2_native(xi.x + xj.x) + 1.f), acc00);
      acc01 = fmaf(v, rcp_native(exp2_native(xi.y + xj.x) + 1.f), acc01);
      acc10 = fmaf(v, rcp_native(exp2_native(xi.x + xj.y) + 1.f), acc10);
      acc11 = fmaf(v, rcp_native(exp2_native(xi.y + xj.y) + 1.f), acc11);
    }
  }
  const float sv = svas;
  float* pout = partials + (size_t)ch * (NB * S * S);
  float2 r0 = {acc00 + sv, acc01 + sv};
  float2 r1 = {acc10 + sv, acc11 + sv};
  *(float2*)&pout[(b * S + a0 + aa) * S + c0 + ca]     = r0;
  *(float2*)&pout[(b * S + a0 + aa + 1) * S + c0 + ca] = r1;
}

// ---------------------------------------------------------------------------
// Stage 3: combine 8 partials -> logits (d_out) + top-4 per row.
__global__ __launch_bounds__(64) void topk_kernel(
    const float* __restrict__ partials, float* __restrict__ logits,
    int* __restrict__ idx) {
  const int row = blockIdx.x;  // b*S + a
  const int lane = threadIdx.x;
  const int P = NB * S * S;
  float v[4];
#pragma unroll
  for (int j = 0; j < 4; ++j) {
    int c = row * S + j * 64 + lane;
    float s0 = partials[c]         + partials[c + P];
    float s1 = partials[c + 2 * P] + partials[c + 3 * P];
    float s2 = partials[c + 4 * P] + partials[c + 5 * P];
    float s3 = partials[c + 6 * P] + partials[c + 7 * P];
    v[j] = (s0 + s1) + (s2 + s3);
    logits[c] = v[j];
  }
#pragma unroll
  for (int k = 0; k < TOPK; ++k) {
    float bestv = v[0];
    int besti = lane;
#pragma unroll
    for (int j = 1; j < 4; ++j) {
      int c = j * 64 + lane;
      if (v[j] > bestv) { bestv = v[j]; besti = c; }
    }
#pragma unroll
    for (int off = 32; off > 0; off >>= 1) {
      float ov = __shfl_xor(bestv, off);
      int oi = __shfl_xor(besti, off);
      if (ov > bestv || (ov == bestv && oi < besti)) { bestv = ov; besti = oi; }
    }
    int mj = besti >> 6, ml = besti & 63;
#pragma unroll
    for (int j = 0; j < 4; ++j)
      if (lane == ml && j == mj) v[j] = -3.402823466e38f;
    if (lane == 0) idx[row * TOPK + k] = besti;
  }
}

// ---------------------------------------------------------------------------
// Stage 4: out_type[r,l] = fc_b[l] + sum_o tanh(dp[b,s,o]+hp[b,idx,o]) * fc_w[l,o]
// One wave per r = (b,s,k). No atomics, no MFMA -- 25 MF + 3.1M tanh total.
__global__ __launch_bounds__(64) void final_kernel(
    const __bf16* __restrict__ dpb, const __bf16* __restrict__ hpb,
    const int* __restrict__ idx, const float* __restrict__ fc_w,
    const float* __restrict__ fc_b, float* __restrict__ out_type) {
  const int r = blockIdx.x;            // 0..4095
  const int kk = r & 3, s = (r >> 2) & 255, b = r >> 10;
  const int hid = idx[(b * S + s) * TOPK + kk];
  const __bf16* dp = dpb + (size_t)(b * S + s) * H;
  const __bf16* hp = hpb + (size_t)(b * S + hid) * H;
  const int lane = threadIdx.x;
  float acc[L] = {};
#pragma unroll
  for (int j = 0; j < 3; ++j) {
    const int o = j * 256 + lane * 4;
    bf16x4 dv = *(const bf16x4*)&dp[o];
    bf16x4 hv = *(const bf16x4*)&hp[o];
    float hd[4];
#pragma unroll
    for (int c = 0; c < 4; ++c)
      hd[c] = fast_tanh((float)dv[c] + (float)hv[c]);
#pragma unroll
    for (int l = 0; l < L; ++l) {
      float4 w = *(const float4*)&fc_w[l * H + o];
      acc[l] = fmaf(hd[0], w.x, acc[l]);
      acc[l] = fmaf(hd[1], w.y, acc[l]);
      acc[l] = fmaf(hd[2], w.z, acc[l]);
      acc[l] = fmaf(hd[3], w.w, acc[l]);
    }
  }
#pragma unroll
  for (int l = 0; l < L; ++l)
#pragma unroll
    for (int off = 32; off > 0; off >>= 1) acc[l] += __shfl_xor(acc[l], off);
  if (lane == 0) {
#pragma unroll
    for (int l = 0; l < L; ++l) out_type[(size_t)r * L + l] = acc[l] + fc_b[l];
  }
}

// ---------------------------------------------------------------------------
extern "C" void kernel_launch(void* const* d_in, const int* in_sizes, int n_in,
                              void* d_out, int out_size, void* d_ws, size_t ws_size,
                              hipStream_t stream) {
  const float* pooled  = (const float*)d_in[0];
  const float* Wa_w    = (const float*)d_in[1];
  const float* Wa_b    = (const float*)d_in[2];
  const float* Ua_w    = (const float*)d_in[3];
  const float* Ua_b    = (const float*)d_in[4];
  const float* va_w    = (const float*)d_in[5];
  const float* dense_w = (const float*)d_in[6];
  const float* dense_b = (const float*)d_in[7];
  const float* fc_w    = (const float*)d_in[8];
  const float* fc_b    = (const float*)d_in[9];

  float* logits   = (float*)d_out;            // (4,256,256)
  float* out_type = logits + NB * S * S;      // (4,256,4,4)

  // ws layout, 4919296 floats = 19.7 MB total (< 22.8 MB known-good from r2).
  // scratch region is time-multiplexed: cvt+big_mfma use Wh/Wl/Ah/Al/Drow,
  // all dead before biaffine overwrites the same region with partials.
  float*  hij     = (float*)d_ws;                   // [0, 1572864)
  float*  scratch = hij + 1572864;                  // [1572864, +2555904)
  float*  partials = scratch;                       //   2097152 f (biaffine/topk)
  __bf16* Wh      = (__bf16*)scratch;               //   1179648 bf16
  __bf16* Wl      = Wh + 1179648;                   //   1179648 bf16
  __bf16* Ah      = Wl + 1179648;                   //   786432 bf16
  __bf16* Al      = Ah + 786432;                    //   786432 bf16
  __bf16* Drow    = Al + 786432;                    //   1179648 bf16 (ends at scratch+2555904 f)
  __bf16* dpb     = (__bf16*)(scratch + 2555904);   // 786432 bf16 (393216 f)
  __bf16* hpb     = dpb + 786432;                   // 786432 bf16 (393216 f)
  int*    idxbuf  = (int*)(hpb + 786432);           // 4096 ints

  cvt_kernel<<<dim3(3072), 256, 0, stream>>>(pooled, Wa_w, Ua_w, dense_w,
                                             Ah, Al, Wh, Wl, Drow);
  big_mfma<<<dim3(32, 48), 256, 0, stream>>>(Ah, Al, Wh, Wl, Drow, Wa_b, Ua_b,
                                             dense_b, hij, dpb, hpb);
  biaffine4<<<dim3(8, 8, NB * NH), 256, 0, stream>>>(hij, va_w, partials);
  topk_kernel<<<dim3(1024), 64, 0, stream>>>(partials, logits, idxbuf);
  final_kernel<<<dim3(4096), 64, 0, stream>>>(dpb, hpb, idxbuf, fc_w, fc_b,
                                              out_type);
}